// Round 8
// baseline (113.510 us; speedup 1.0000x reference)
//
#include <hip/hip_runtime.h>
#include <math.h>

// MoE router: logits = x @ gate_w  (M=32768, K=2048, N=64 fp32)
// Split-precision MFMA: x,w -> 2 fp16 limbs each; logits = xh*wh + xh*wl + xl*wh.
// Scaling: x*64, w*256 (denormal safety), descale 2^-14 at epilogue.
// R8: wave = 16 tokens x 64 experts x full K; B shared across waves;
//     double-buffered staging with counted vmcnt + raw s_barrier pipeline.
// outputs (concat flat, read back as float32):
//   [0 .. 2N)   top_k_weights [N,2]
//   [2N .. 4N)  top_k_indices [N,2] (as float values)
//   [4N]        load_balance_loss scalar
#define N_TOKENS 32768
#define HIDDEN   2048
#define NEXP     64
#define BM 64                   // tokens per block
#define NWAVE 4                 // 256 threads; wave rw owns tokens rw*16..+15
#define NBLK (N_TOKENS / BM)    // 512
#define KSTEP 32
#define NSTEP (HIDDEN / KSTEP)  // 64
#define XSCALE 64.f
#define WSCALE 256.f
#define DESCALE (1.f / 16384.f)
#define LGS 68                  // logits row stride (2-way banks on store, free)

typedef __attribute__((ext_vector_type(8))) _Float16 half8;
typedef __attribute__((ext_vector_type(4))) float f32x4;

__device__ __forceinline__ void gload16(const void* g, void* l) {
    __builtin_amdgcn_global_load_lds(
        (const __attribute__((address_space(1))) void*)g,
        (__attribute__((address_space(3))) void*)l, 16, 0, 0);
}

// ---- kernel 0: split gate_w into 2 fp16 limb planes, MFMA-fragment-packed ----
// plane order: [(S*4 + nt)*64 + lane]*8 + j  <=>  w[32S + (lane>>4)*8 + j][nt*16 + (lane&15)]
__global__ void wsplit_kernel(const float* __restrict__ gw,
                              _Float16* __restrict__ wh, _Float16* __restrict__ wl) {
    const int S   = blockIdx.x;          // 0..63 K-steps
    const int tid = threadIdx.x;         // 256
    const int nt  = tid >> 6;
    const int l   = tid & 63;
    const int col = nt * 16 + (l & 15);
    const int krow = 32 * S + (l >> 4) * 8;
    half8 vh, vl;
    #pragma unroll
    for (int j = 0; j < 8; ++j) {
        const float w = gw[(size_t)(krow + j) * NEXP + col] * WSCALE;
        const _Float16 hh = (_Float16)w;
        vh[j] = hh;
        vl[j] = (_Float16)(w - (float)hh);
    }
    const size_t off = ((size_t)(S * 4 + nt) * 64 + l) * 8;
    *reinterpret_cast<half8*>(wh + off) = vh;
    *reinterpret_cast<half8*>(wl + off) = vl;
}

__global__ __launch_bounds__(256, 2)
void router_main(const float* __restrict__ x,
                 const _Float16* __restrict__ whp, const _Float16* __restrict__ wlp,
                 float* __restrict__ out_w, float* __restrict__ out_i,
                 float* __restrict__ wsP, int* __restrict__ wsC)
{
    // [0..4095]: B tiles as half[2 buf][2 limb][4 nt][512]; [4096..8191]: A tiles [2 buf][4 wv][512]
    // after K-loop the arena is reused as logits[64][LGS]
    __shared__ __align__(16) float arena[8192];   // 32 KB
    __shared__ float pred[NWAVE][NEXP];
    __shared__ int   cntl[NEXP];

    const int tid  = threadIdx.x;
    const int lane = tid & 63;
    const int rw   = __builtin_amdgcn_readfirstlane(tid >> 6);
    const int m0   = blockIdx.x * BM;
    if (tid < NEXP) cntl[tid] = 0;

    _Float16* const bt = reinterpret_cast<_Float16*>(arena);   // halfs
    float* const at    = arena + 4096;

    // A staging decomposition (XOR-swizzled global source, linear LDS dest)
    const int stok = lane >> 3;              // token within 8-row group
    const int su   = (lane & 7) ^ stok;      // swizzled 16B unit

    f32x4 acc[4];
    const f32x4 zero = {0.f, 0.f, 0.f, 0.f};
    #pragma unroll
    for (int nt = 0; nt < 4; ++nt) acc[nt] = zero;

    #define STAGE(s, b)                                                                 \
        {                                                                               \
            const int k0_ = (s) * KSTEP;                                                \
            _Pragma("unroll")                                                           \
            for (int i = 0; i < 2; ++i) {                                               \
                const float* g_ = x + (size_t)(m0 + rw * 16 + i * 8 + stok) * HIDDEN    \
                                    + k0_ + su * 4;                                     \
                gload16(g_, at + ((b) * 4 + rw) * 512 + i * 256);                       \
            }                                                                           \
            gload16(whp + ((size_t)((s) * 4 + rw) * 64 + lane) * 8,                     \
                    bt + (((b) * 2 + 0) * 4 + rw) * 512);                               \
            gload16(wlp + ((size_t)((s) * 4 + rw) * 64 + lane) * 8,                     \
                    bt + (((b) * 2 + 1) * 4 + rw) * 512);                               \
        }

    // prologue
    STAGE(0, 0);

    for (int s = 0; s < NSTEP; ++s) {
        const int b = s & 1;
        if (s + 1 < NSTEP) {
            STAGE(s + 1, b ^ 1);
            asm volatile("s_waitcnt vmcnt(4)" ::: "memory");   // step-s loads retired
        } else {
            asm volatile("s_waitcnt vmcnt(0)" ::: "memory");
        }
        __builtin_amdgcn_sched_barrier(0);
        __builtin_amdgcn_s_barrier();      // raw barrier: in-flight loads stay in flight

        // ---- compute step s from buffer b ----
        // B fragments: per-lane 16B, conflict-free
        half8 bfh[4], bfl[4];
        #pragma unroll
        for (int nt = 0; nt < 4; ++nt) {
            bfh[nt] = *reinterpret_cast<const half8*>(bt + ((b * 2 + 0) * 4 + nt) * 512 + lane * 8);
            bfl[nt] = *reinterpret_cast<const half8*>(bt + ((b * 2 + 1) * 4 + nt) * 512 + lane * 8);
        }
        // A fragment: read fp32 (swizzled units), scale + split into 2 fp16 limbs
        {
            const float* abase = at + (b * 4 + rw) * 512;
            const int row = lane & 15;
            const int t7  = lane & 7;          // row & 7
            const int vb  = (lane >> 4) * 2;
            const float* xrow = abase + row * 32;
            const f32x4 q0 = *reinterpret_cast<const f32x4*>(xrow + ((vb ^ t7) << 2));
            const f32x4 q1 = *reinterpret_cast<const f32x4*>(xrow + (((vb + 1) ^ t7) << 2));
            half8 ah, al;
            #pragma unroll
            for (int j = 0; j < 4; ++j) {
                const float v = q0[j] * XSCALE;
                const _Float16 hh = (_Float16)v;
                ah[j] = hh; al[j] = (_Float16)(v - (float)hh);
            }
            #pragma unroll
            for (int j = 0; j < 4; ++j) {
                const float v = q1[j] * XSCALE;
                const _Float16 hh = (_Float16)v;
                ah[4 + j] = hh; al[4 + j] = (_Float16)(v - (float)hh);
            }
            #pragma unroll
            for (int nt = 0; nt < 4; ++nt) {
                f32x4 c = acc[nt];
                c = __builtin_amdgcn_mfma_f32_16x16x32_f16(ah, bfh[nt], c, 0, 0, 0);
                c = __builtin_amdgcn_mfma_f32_16x16x32_f16(ah, bfl[nt], c, 0, 0, 0);
                c = __builtin_amdgcn_mfma_f32_16x16x32_f16(al, bfh[nt], c, 0, 0, 0);
                acc[nt] = c;
            }
        }
        asm volatile("s_waitcnt lgkmcnt(0)" ::: "memory");     // my ds_reads retired
        __builtin_amdgcn_sched_barrier(0);
        __builtin_amdgcn_s_barrier();      // everyone done reading buffer b
    }

    // dump logits (arena reused): C/D layout col=lane&15, row=(lane>>4)*4+reg (m89-verified)
    #pragma unroll
    for (int nt = 0; nt < 4; ++nt)
        #pragma unroll
        for (int r = 0; r < 4; ++r)
            arena[(rw * 16 + (lane >> 4) * 4 + r) * LGS + nt * 16 + (lane & 15)] =
                acc[nt][r] * DESCALE;
    __syncthreads();

    // epilogue: wave rw handles its own tokens rw*16..+15; lane = expert
    float sumP = 0.f;
    for (int t = 0; t < 16; ++t) {
        const int m = rw * 16 + t;
        const float l = arena[m * LGS + lane];

        // top-1 (max value, lowest index on tie — matches jax.lax.top_k)
        float v = l; int idx = lane;
        #pragma unroll
        for (int off = 32; off >= 1; off >>= 1) {
            float ov = __shfl_xor(v, off);
            int   oi = __shfl_xor(idx, off);
            if (ov > v || (ov == v && oi < idx)) { v = ov; idx = oi; }
        }
        const float v1 = v; const int i1 = idx;
        // top-2
        v = (lane == i1) ? -INFINITY : l;
        idx = lane;
        #pragma unroll
        for (int off = 32; off >= 1; off >>= 1) {
            float ov = __shfl_xor(v, off);
            int   oi = __shfl_xor(idx, off);
            if (ov > v || (ov == v && oi < idx)) { v = ov; idx = oi; }
        }
        const float v2 = v; const int i2 = idx;
        // softmax over the two top logits (stable: v2 - v1 <= 0)
        const float ed  = expf(v2 - v1);
        const float wt1 = 1.f / (1.f + ed);
        const float wt2 = ed / (1.f + ed);
        // full softmax over 64 experts (max is v1)
        const float p = expf(l - v1);
        float Z = p;
        #pragma unroll
        for (int off = 32; off >= 1; off >>= 1) Z += __shfl_xor(Z, off);
        sumP += p / Z;
        if (lane == 0) {
            const size_t o = (size_t)(m0 + m) * 2;
            out_w[o]     = wt1;
            out_w[o + 1] = wt2;
            out_i[o]     = (float)i1;
            out_i[o + 1] = (float)i2;
            atomicAdd(&cntl[i1], 1);
            atomicAdd(&cntl[i2], 1);
        }
    }
    pred[rw][lane] = sumP;
    __syncthreads();
    if (tid < NEXP) {
        float s = 0.f;
        #pragma unroll
        for (int w2 = 0; w2 < NWAVE; ++w2) s += pred[w2][tid];
        wsP[(size_t)blockIdx.x * NEXP + tid] = s;
        wsC[(size_t)blockIdx.x * NEXP + tid] = cntl[tid];
    }
}

__global__ void router_finalize(const float* __restrict__ wsP, const int* __restrict__ wsC,
                                float* __restrict__ out_loss)
{
    const int e = threadIdx.x;   // 64 threads, lane = expert
    float P = 0.f, C = 0.f;
    #pragma unroll 8
    for (int b = 0; b < NBLK; ++b) {
        P += wsP[(size_t)b * NEXP + e];
        C += (float)wsC[(size_t)b * NEXP + e];
    }
    float val = (C / (float)N_TOKENS) * (P / (float)N_TOKENS);
    #pragma unroll
    for (int off = 32; off >= 1; off >>= 1) val += __shfl_xor(val, off);
    if (e == 0) out_loss[0] = (float)NEXP * val;
}

extern "C" void kernel_launch(void* const* d_in, const int* in_sizes, int n_in,
                              void* d_out, int out_size, void* d_ws, size_t ws_size,
                              hipStream_t stream) {
    const float* x  = (const float*)d_in[0];
    const float* gw = (const float*)d_in[1];
    float* out   = (float*)d_out;
    float* out_w = out;                        // [N,2] weights
    float* out_i = out + (size_t)N_TOKENS * 2; // [N,2] indices (as floats)
    float* loss  = out + (size_t)N_TOKENS * 4; // scalar
    float*    wsP = (float*)d_ws;                                    // 128 KB
    int*      wsC = (int*)((char*)d_ws + 131072);                    // 128 KB
    _Float16* wh  = (_Float16*)((char*)d_ws + 262144);               // 256 KB
    _Float16* wl  = wh + (size_t)HIDDEN * NEXP;                      // 256 KB
    hipLaunchKernelGGL(wsplit_kernel, dim3(HIDDEN / KSTEP), dim3(256), 0, stream, gw, wh, wl);
    hipLaunchKernelGGL(router_main, dim3(NBLK), dim3(256), 0, stream,
                       x, wh, wl, out_w, out_i, wsP, wsC);
    hipLaunchKernelGGL(router_finalize, dim3(1), dim3(64), 0, stream, wsP, wsC, loss);
}

// Round 9
// 93.534 us; speedup vs baseline: 1.2136x; 1.2136x over previous
//
#include <hip/hip_runtime.h>
#include <math.h>

// MoE router: logits = x @ gate_w  (M=32768, K=2048, N=64 fp32)
// Split-precision MFMA: x,w -> 2 fp16 limbs each; logits = xh*wh + xh*wl + xl*wh.
// Scaling: x*64, w*256 (denormal safety), descale 2^-14 at epilogue.
// R9: all-register pipeline. wave = 32 tokens x 64 experts x K-half.
//     A and B frags loaded straight to VGPRs (no LDS staging, no K-loop barriers),
//     register double-buffer with static set indices (2x-unrolled loop body).
// outputs (concat flat, read back as float32):
//   [0 .. 2N)   top_k_weights [N,2]
//   [2N .. 4N)  top_k_indices [N,2] (as float values)
//   [4N]        load_balance_loss scalar
#define N_TOKENS 32768
#define HIDDEN   2048
#define NEXP     64
#define BM 64                   // tokens per block
#define NWAVE 4                 // 256 threads
#define NBLK (N_TOKENS / BM)    // 512
#define KSTEP 32
#define NSTEP 32                // K-half (1024) / KSTEP
#define XSCALE 64.f
#define WSCALE 256.f
#define DESCALE (1.f / 16384.f)

typedef __attribute__((ext_vector_type(8))) _Float16 half8;
typedef __attribute__((ext_vector_type(4))) float f32x4;

// ---- kernel 0: split gate_w into 2 fp16 limb planes, MFMA-fragment-packed ----
// plane order: [(S*4 + nt)*64 + lane]*8 + j  <=>  w[32S + (lane>>4)*8 + j][nt*16 + (lane&15)]
__global__ void wsplit_kernel(const float* __restrict__ gw,
                              _Float16* __restrict__ wh, _Float16* __restrict__ wl) {
    __shared__ float tile[KSTEP * NEXP];     // 32 k-rows x 64 experts
    const int S   = blockIdx.x;              // 0..63 K-steps
    const int tid = threadIdx.x;             // 256
    // coalesced tile load: 512 float4
    const float4* g4 = reinterpret_cast<const float4*>(gw + (size_t)S * KSTEP * NEXP);
    float4* t4 = reinterpret_cast<float4*>(tile);
    t4[tid]       = g4[tid];
    t4[tid + 256] = g4[tid + 256];
    __syncthreads();
    const int nt  = tid >> 6;
    const int l   = tid & 63;
    const int col = nt * 16 + (l & 15);
    const int kr  = (l >> 4) * 8;
    half8 vh, vl;
    #pragma unroll
    for (int j = 0; j < 8; ++j) {
        const float w = tile[(kr + j) * NEXP + col] * WSCALE;
        const _Float16 hh = (_Float16)w;
        vh[j] = hh;
        vl[j] = (_Float16)(w - (float)hh);
    }
    const size_t off = ((size_t)(S * 4 + nt) * 64 + l) * 8;
    *reinterpret_cast<half8*>(wh + off) = vh;
    *reinterpret_cast<half8*>(wl + off) = vl;
}

__global__ __launch_bounds__(256, 2)
void router_main(const float* __restrict__ x,
                 const _Float16* __restrict__ whp, const _Float16* __restrict__ wlp,
                 float* __restrict__ out_w, float* __restrict__ out_i,
                 float* __restrict__ wsP, int* __restrict__ wsC)
{
    __shared__ float part[2][BM][65];   // K-half partial logits (33.3 KB)
    __shared__ float pred[NWAVE][NEXP];
    __shared__ int   cntl[NEXP];

    const int tid  = threadIdx.x;
    const int lane = tid & 63;
    const int wv   = tid >> 6;
    const int m0   = blockIdx.x * BM;
    if (tid < NEXP) cntl[tid] = 0;

    const int mrow = lane & 15;        // token row within m-tile (= C col-lane role for A)
    const int kq   = lane >> 4;        // k quad
    const int wtok = (wv >> 1) * 32;   // wave token base: 0 or 32
    const int kh   = wv & 1;           // K-half
    const int Sb   = kh * NSTEP;       // global K-step base

    const float* xb = x + (size_t)(m0 + wtok + mrow) * HIDDEN + (size_t)kh * 1024 + kq * 8;

    f32x4 a[2][2][2];                  // [set][mt][half-of-8]
    half8 bh[2][4], bl[2][4];          // [set][nt]
    f32x4 acc[2][4];
    const f32x4 zero = {0.f, 0.f, 0.f, 0.f};
    #pragma unroll
    for (int mt = 0; mt < 2; ++mt)
        #pragma unroll
        for (int nt = 0; nt < 4; ++nt) acc[mt][nt] = zero;

    #define LOADA(SET, s_) {                                                          \
        _Pragma("unroll")                                                             \
        for (int mt = 0; mt < 2; ++mt) {                                              \
            const float* g_ = xb + (size_t)mt * (16 * HIDDEN) + (s_) * KSTEP;         \
            a[SET][mt][0] = *reinterpret_cast<const f32x4*>(g_);                      \
            a[SET][mt][1] = *reinterpret_cast<const f32x4*>(g_ + 4);                  \
        } }
    #define LOADB(SET, s_) {                                                          \
        const int S_ = Sb + (s_);                                                     \
        _Pragma("unroll")                                                             \
        for (int nt = 0; nt < 4; ++nt) {                                              \
            const size_t o_ = ((size_t)(S_ * 4 + nt) * 64 + lane) * 8;                \
            bh[SET][nt] = *reinterpret_cast<const half8*>(whp + o_);                  \
            bl[SET][nt] = *reinterpret_cast<const half8*>(wlp + o_);                  \
        } }
    #define COMPUTE(SET) {                                                            \
        half8 ah[2], al[2];                                                           \
        _Pragma("unroll")                                                             \
        for (int mt = 0; mt < 2; ++mt)                                                \
            _Pragma("unroll")                                                         \
            for (int h = 0; h < 2; ++h)                                               \
                _Pragma("unroll")                                                     \
                for (int j = 0; j < 4; ++j) {                                         \
                    const float v_ = a[SET][mt][h][j] * XSCALE;                       \
                    const _Float16 hh_ = (_Float16)v_;                                \
                    ah[mt][h * 4 + j] = hh_;                                          \
                    al[mt][h * 4 + j] = (_Float16)(v_ - (float)hh_);                  \
                }                                                                     \
        _Pragma("unroll")                                                             \
        for (int mt = 0; mt < 2; ++mt)                                                \
            _Pragma("unroll")                                                         \
            for (int nt = 0; nt < 4; ++nt) {                                          \
                f32x4 c_ = acc[mt][nt];                                               \
                c_ = __builtin_amdgcn_mfma_f32_16x16x32_f16(ah[mt], bh[SET][nt], c_, 0, 0, 0); \
                c_ = __builtin_amdgcn_mfma_f32_16x16x32_f16(ah[mt], bl[SET][nt], c_, 0, 0, 0); \
                c_ = __builtin_amdgcn_mfma_f32_16x16x32_f16(al[mt], bh[SET][nt], c_, 0, 0, 0); \
                acc[mt][nt] = c_;                                                     \
            } }

    // prologue + 2x-unrolled steady state (static register-set indices)
    LOADA(0, 0); LOADB(0, 0);
    for (int s = 0; s < NSTEP; s += 2) {
        LOADA(1, s + 1); LOADB(1, s + 1);      // s+1 <= 31 always valid
        COMPUTE(0);
        if (s + 2 < NSTEP) { LOADA(0, s + 2); LOADB(0, s + 2); }
        COMPUTE(1);
    }
    #undef LOADA
    #undef LOADB
    #undef COMPUTE

    // dump K-half partials: C/D layout col=lane&15 (expert), row=(lane>>4)*4+r (token)
    #pragma unroll
    for (int mt = 0; mt < 2; ++mt)
        #pragma unroll
        for (int nt = 0; nt < 4; ++nt)
            #pragma unroll
            for (int r = 0; r < 4; ++r)
                part[kh][wtok + mt * 16 + (lane >> 4) * 4 + r][nt * 16 + (lane & 15)] =
                    acc[mt][nt][r] * DESCALE;
    __syncthreads();

    // epilogue: wave wv handles tokens wv*16..+15; lane = expert
    float sumP = 0.f;
    for (int t = 0; t < 16; ++t) {
        const int m = wv * 16 + t;
        const float l = part[0][m][lane] + part[1][m][lane];

        // top-1 (max value, lowest index on tie — matches jax.lax.top_k)
        float v = l; int idx = lane;
        #pragma unroll
        for (int off = 32; off >= 1; off >>= 1) {
            float ov = __shfl_xor(v, off);
            int   oi = __shfl_xor(idx, off);
            if (ov > v || (ov == v && oi < idx)) { v = ov; idx = oi; }
        }
        const float v1 = v; const int i1 = idx;
        // top-2
        v = (lane == i1) ? -INFINITY : l;
        idx = lane;
        #pragma unroll
        for (int off = 32; off >= 1; off >>= 1) {
            float ov = __shfl_xor(v, off);
            int   oi = __shfl_xor(idx, off);
            if (ov > v || (ov == v && oi < idx)) { v = ov; idx = oi; }
        }
        const float v2 = v; const int i2 = idx;
        // softmax over the two top logits (stable: v2 - v1 <= 0)
        const float ed  = expf(v2 - v1);
        const float wt1 = 1.f / (1.f + ed);
        const float wt2 = ed / (1.f + ed);
        // full softmax over 64 experts (max is v1)
        const float p = expf(l - v1);
        float Z = p;
        #pragma unroll
        for (int off = 32; off >= 1; off >>= 1) Z += __shfl_xor(Z, off);
        sumP += p / Z;
        if (lane == 0) {
            const size_t o = (size_t)(m0 + m) * 2;
            out_w[o]     = wt1;
            out_w[o + 1] = wt2;
            out_i[o]     = (float)i1;
            out_i[o + 1] = (float)i2;
            atomicAdd(&cntl[i1], 1);
            atomicAdd(&cntl[i2], 1);
        }
    }
    pred[wv][lane] = sumP;
    __syncthreads();
    if (tid < NEXP) {
        float s = 0.f;
        #pragma unroll
        for (int w2 = 0; w2 < NWAVE; ++w2) s += pred[w2][tid];
        wsP[(size_t)blockIdx.x * NEXP + tid] = s;
        wsC[(size_t)blockIdx.x * NEXP + tid] = cntl[tid];
    }
}

__global__ void router_finalize(const float* __restrict__ wsP, const int* __restrict__ wsC,
                                float* __restrict__ out_loss)
{
    __shared__ float red[16][16][8];
    const int tid = threadIdx.x;       // 256
    const int e4  = tid & 15;          // expert quad
    const int q   = tid >> 4;          // block slice (32 blocks each)
    float p0 = 0.f, p1 = 0.f, p2 = 0.f, p3 = 0.f;
    float c0 = 0.f, c1 = 0.f, c2 = 0.f, c3 = 0.f;
    #pragma unroll 4
    for (int b = q * 32; b < q * 32 + 32; ++b) {
        const float4 p = *reinterpret_cast<const float4*>(wsP + (size_t)b * NEXP + e4 * 4);
        const int4   c = *reinterpret_cast<const int4*>(wsC + (size_t)b * NEXP + e4 * 4);
        p0 += p.x; p1 += p.y; p2 += p.z; p3 += p.w;
        c0 += (float)c.x; c1 += (float)c.y; c2 += (float)c.z; c3 += (float)c.w;
    }
    red[q][e4][0] = p0; red[q][e4][1] = p1; red[q][e4][2] = p2; red[q][e4][3] = p3;
    red[q][e4][4] = c0; red[q][e4][5] = c1; red[q][e4][6] = c2; red[q][e4][7] = c3;
    __syncthreads();
    if (tid < NEXP) {
        float P = 0.f, C = 0.f;
        #pragma unroll
        for (int qq = 0; qq < 16; ++qq) {
            P += red[qq][tid >> 2][tid & 3];
            C += red[qq][tid >> 2][4 + (tid & 3)];
        }
        float val = (C / (float)N_TOKENS) * (P / (float)N_TOKENS);
        #pragma unroll
        for (int off = 32; off >= 1; off >>= 1) val += __shfl_xor(val, off);
        if (tid == 0) out_loss[0] = (float)NEXP * val;
    }
}

extern "C" void kernel_launch(void* const* d_in, const int* in_sizes, int n_in,
                              void* d_out, int out_size, void* d_ws, size_t ws_size,
                              hipStream_t stream) {
    const float* x  = (const float*)d_in[0];
    const float* gw = (const float*)d_in[1];
    float* out   = (float*)d_out;
    float* out_w = out;                        // [N,2] weights
    float* out_i = out + (size_t)N_TOKENS * 2; // [N,2] indices (as floats)
    float* loss  = out + (size_t)N_TOKENS * 4; // scalar
    float*    wsP = (float*)d_ws;                                    // 128 KB
    int*      wsC = (int*)((char*)d_ws + 131072);                    // 128 KB
    _Float16* wh  = (_Float16*)((char*)d_ws + 262144);               // 256 KB
    _Float16* wl  = wh + (size_t)HIDDEN * NEXP;                      // 256 KB
    hipLaunchKernelGGL(wsplit_kernel, dim3(HIDDEN / KSTEP), dim3(256), 0, stream, gw, wh, wl);
    hipLaunchKernelGGL(router_main, dim3(NBLK), dim3(256), 0, stream,
                       x, wh, wl, out_w, out_i, wsP, wsC);
    hipLaunchKernelGGL(router_finalize, dim3(1), dim3(256), 0, stream, wsP, wsC, loss);
}

// Round 10
// 91.896 us; speedup vs baseline: 1.2352x; 1.0178x over previous
//
#include <hip/hip_runtime.h>
#include <math.h>

// MoE router: logits = x @ gate_w  (M=32768, K=2048, N=64 fp32)
// Split-precision MFMA: x,w -> 2 fp16 limbs each; logits = xh*wh + xh*wl + xl*wh.
// Scaling: x*64, w*256 (denormal safety), descale 2^-14 at epilogue.
// R10: all-register pipeline, deepened: A (HBM) prefetched 3 steps ahead (4 sets),
//      B (L2) 1 step ahead (2 sets). Static set indices, no LDS/barriers in K-loop.
// outputs (concat flat, read back as float32):
//   [0 .. 2N)   top_k_weights [N,2]
//   [2N .. 4N)  top_k_indices [N,2] (as float values)
//   [4N]        load_balance_loss scalar
#define N_TOKENS 32768
#define HIDDEN   2048
#define NEXP     64
#define BM 64                   // tokens per block
#define NWAVE 4                 // 256 threads
#define NBLK (N_TOKENS / BM)    // 512
#define KSTEP 32
#define NSTEP 32                // K-half (1024) / KSTEP
#define XSCALE 64.f
#define WSCALE 256.f
#define DESCALE (1.f / 16384.f)

typedef __attribute__((ext_vector_type(8))) _Float16 half8;
typedef __attribute__((ext_vector_type(4))) float f32x4;

// ---- kernel 0: split gate_w into 2 fp16 limb planes, MFMA-fragment-packed ----
// plane order: [(S*4 + nt)*64 + lane]*8 + j  <=>  w[32S + (lane>>4)*8 + j][nt*16 + (lane&15)]
__global__ void wsplit_kernel(const float* __restrict__ gw,
                              _Float16* __restrict__ wh, _Float16* __restrict__ wl) {
    __shared__ float tile[KSTEP * NEXP];     // 32 k-rows x 64 experts
    const int S   = blockIdx.x;              // 0..63 K-steps
    const int tid = threadIdx.x;             // 256
    const float4* g4 = reinterpret_cast<const float4*>(gw + (size_t)S * KSTEP * NEXP);
    float4* t4 = reinterpret_cast<float4*>(tile);
    t4[tid]       = g4[tid];
    t4[tid + 256] = g4[tid + 256];
    __syncthreads();
    const int nt  = tid >> 6;
    const int l   = tid & 63;
    const int col = nt * 16 + (l & 15);
    const int kr  = (l >> 4) * 8;
    half8 vh, vl;
    #pragma unroll
    for (int j = 0; j < 8; ++j) {
        const float w = tile[(kr + j) * NEXP + col] * WSCALE;
        const _Float16 hh = (_Float16)w;
        vh[j] = hh;
        vl[j] = (_Float16)(w - (float)hh);
    }
    const size_t off = ((size_t)(S * 4 + nt) * 64 + l) * 8;
    *reinterpret_cast<half8*>(wh + off) = vh;
    *reinterpret_cast<half8*>(wl + off) = vl;
}

__global__ __launch_bounds__(256, 2)
void router_main(const float* __restrict__ x,
                 const _Float16* __restrict__ whp, const _Float16* __restrict__ wlp,
                 float* __restrict__ out_w, float* __restrict__ out_i,
                 float* __restrict__ wsP, int* __restrict__ wsC)
{
    __shared__ float part[2][BM][65];   // K-half partial logits (33.3 KB)
    __shared__ float pred[NWAVE][NEXP];
    __shared__ int   cntl[NEXP];

    const int tid  = threadIdx.x;
    const int lane = tid & 63;
    const int wv   = tid >> 6;
    const int m0   = blockIdx.x * BM;
    if (tid < NEXP) cntl[tid] = 0;

    const int mrow = lane & 15;        // token row within m-tile
    const int kq   = lane >> 4;        // k quad
    const int wtok = (wv >> 1) * 32;   // wave token base: 0 or 32
    const int kh   = wv & 1;           // K-half
    const int Sb   = kh * NSTEP;       // global K-step base

    const float* xb = x + (size_t)(m0 + wtok + mrow) * HIDDEN + (size_t)kh * 1024 + kq * 8;

    f32x4 a[4][2][2];                  // [set][mt][half-of-8] — A prefetch depth 3
    half8 bh[2][4], bl[2][4];          // [set][nt]            — B prefetch depth 1
    f32x4 acc[2][4];
    const f32x4 zero = {0.f, 0.f, 0.f, 0.f};
    #pragma unroll
    for (int mt = 0; mt < 2; ++mt)
        #pragma unroll
        for (int nt = 0; nt < 4; ++nt) acc[mt][nt] = zero;

    #define LOADA(SET, s_) {                                                          \
        _Pragma("unroll")                                                             \
        for (int mt = 0; mt < 2; ++mt) {                                              \
            const float* g_ = xb + (size_t)mt * (16 * HIDDEN) + (s_) * KSTEP;         \
            a[SET][mt][0] = *reinterpret_cast<const f32x4*>(g_);                      \
            a[SET][mt][1] = *reinterpret_cast<const f32x4*>(g_ + 4);                  \
        } }
    #define LOADB(SET, s_) {                                                          \
        const int S_ = Sb + (s_);                                                     \
        _Pragma("unroll")                                                             \
        for (int nt = 0; nt < 4; ++nt) {                                              \
            const size_t o_ = ((size_t)(S_ * 4 + nt) * 64 + lane) * 8;                \
            bh[SET][nt] = *reinterpret_cast<const half8*>(whp + o_);                  \
            bl[SET][nt] = *reinterpret_cast<const half8*>(wlp + o_);                  \
        } }
    #define COMPUTE(AS, BS) {                                                         \
        half8 ah[2], al[2];                                                           \
        _Pragma("unroll")                                                             \
        for (int mt = 0; mt < 2; ++mt)                                                \
            _Pragma("unroll")                                                         \
            for (int h = 0; h < 2; ++h)                                               \
                _Pragma("unroll")                                                     \
                for (int j = 0; j < 4; ++j) {                                         \
                    const float v_ = a[AS][mt][h][j] * XSCALE;                        \
                    const _Float16 hh_ = (_Float16)v_;                                \
                    ah[mt][h * 4 + j] = hh_;                                          \
                    al[mt][h * 4 + j] = (_Float16)(v_ - (float)hh_);                  \
                }                                                                     \
        _Pragma("unroll")                                                             \
        for (int mt = 0; mt < 2; ++mt)                                                \
            _Pragma("unroll")                                                         \
            for (int nt = 0; nt < 4; ++nt) {                                          \
                f32x4 c_ = acc[mt][nt];                                               \
                c_ = __builtin_amdgcn_mfma_f32_16x16x32_f16(ah[mt], bh[BS][nt], c_, 0, 0, 0); \
                c_ = __builtin_amdgcn_mfma_f32_16x16x32_f16(ah[mt], bl[BS][nt], c_, 0, 0, 0); \
                c_ = __builtin_amdgcn_mfma_f32_16x16x32_f16(al[mt], bh[BS][nt], c_, 0, 0, 0); \
                acc[mt][nt] = c_;                                                     \
            } }

    // prologue: A 3 deep, B 1 deep
    LOADA(0, 0); LOADA(1, 1); LOADA(2, 2); LOADB(0, 0);

    // steady state: 4-step body, all set indices static
    for (int t = 0; t < 7; ++t) {
        const int s = t * 4;
        LOADA(3, s + 3); LOADB(1, s + 1); COMPUTE(0, 0);
        LOADA(0, s + 4); LOADB(0, s + 2); COMPUTE(1, 1);
        LOADA(1, s + 5); LOADB(1, s + 3); COMPUTE(2, 0);
        LOADA(2, s + 6); LOADB(0, s + 4); COMPUTE(3, 1);
    }
    // tail: steps 28..31
    LOADA(3, 31); LOADB(1, 29); COMPUTE(0, 0);
    LOADB(0, 30); COMPUTE(1, 1);
    LOADB(1, 31); COMPUTE(2, 0);
    COMPUTE(3, 1);
    #undef LOADA
    #undef LOADB
    #undef COMPUTE

    // dump K-half partials: C/D layout col=lane&15 (expert), row=(lane>>4)*4+r (token)
    #pragma unroll
    for (int mt = 0; mt < 2; ++mt)
        #pragma unroll
        for (int nt = 0; nt < 4; ++nt)
            #pragma unroll
            for (int r = 0; r < 4; ++r)
                part[kh][wtok + mt * 16 + (lane >> 4) * 4 + r][nt * 16 + (lane & 15)] =
                    acc[mt][nt][r] * DESCALE;
    __syncthreads();

    // epilogue: wave wv handles tokens wv*16..+15; lane = expert
    float sumP = 0.f;
    for (int t = 0; t < 16; ++t) {
        const int m = wv * 16 + t;
        const float l = part[0][m][lane] + part[1][m][lane];

        // top-1 (max value, lowest index on tie — matches jax.lax.top_k)
        float v = l; int idx = lane;
        #pragma unroll
        for (int off = 32; off >= 1; off >>= 1) {
            float ov = __shfl_xor(v, off);
            int   oi = __shfl_xor(idx, off);
            if (ov > v || (ov == v && oi < idx)) { v = ov; idx = oi; }
        }
        const float v1 = v; const int i1 = idx;
        // top-2
        v = (lane == i1) ? -INFINITY : l;
        idx = lane;
        #pragma unroll
        for (int off = 32; off >= 1; off >>= 1) {
            float ov = __shfl_xor(v, off);
            int   oi = __shfl_xor(idx, off);
            if (ov > v || (ov == v && oi < idx)) { v = ov; idx = oi; }
        }
        const float v2 = v; const int i2 = idx;
        // softmax over the two top logits (stable: v2 - v1 <= 0)
        const float ed  = expf(v2 - v1);
        const float wt1 = 1.f / (1.f + ed);
        const float wt2 = ed / (1.f + ed);
        // full softmax over 64 experts (max is v1)
        const float p = expf(l - v1);
        float Z = p;
        #pragma unroll
        for (int off = 32; off >= 1; off >>= 1) Z += __shfl_xor(Z, off);
        sumP += p / Z;
        if (lane == 0) {
            const size_t o = (size_t)(m0 + m) * 2;
            out_w[o]     = wt1;
            out_w[o + 1] = wt2;
            out_i[o]     = (float)i1;
            out_i[o + 1] = (float)i2;
            atomicAdd(&cntl[i1], 1);
            atomicAdd(&cntl[i2], 1);
        }
    }
    pred[wv][lane] = sumP;
    __syncthreads();
    if (tid < NEXP) {
        float s = 0.f;
        #pragma unroll
        for (int w2 = 0; w2 < NWAVE; ++w2) s += pred[w2][tid];
        wsP[(size_t)blockIdx.x * NEXP + tid] = s;
        wsC[(size_t)blockIdx.x * NEXP + tid] = cntl[tid];
    }
}

__global__ void router_finalize(const float* __restrict__ wsP, const int* __restrict__ wsC,
                                float* __restrict__ out_loss)
{
    __shared__ float red[16][16][8];
    const int tid = threadIdx.x;       // 256
    const int e4  = tid & 15;          // expert quad
    const int q   = tid >> 4;          // block slice (32 blocks each)
    float p0 = 0.f, p1 = 0.f, p2 = 0.f, p3 = 0.f;
    float c0 = 0.f, c1 = 0.f, c2 = 0.f, c3 = 0.f;
    #pragma unroll 4
    for (int b = q * 32; b < q * 32 + 32; ++b) {
        const float4 p = *reinterpret_cast<const float4*>(wsP + (size_t)b * NEXP + e4 * 4);
        const int4   c = *reinterpret_cast<const int4*>(wsC + (size_t)b * NEXP + e4 * 4);
        p0 += p.x; p1 += p.y; p2 += p.z; p3 += p.w;
        c0 += (float)c.x; c1 += (float)c.y; c2 += (float)c.z; c3 += (float)c.w;
    }
    red[q][e4][0] = p0; red[q][e4][1] = p1; red[q][e4][2] = p2; red[q][e4][3] = p3;
    red[q][e4][4] = c0; red[q][e4][5] = c1; red[q][e4][6] = c2; red[q][e4][7] = c3;
    __syncthreads();
    if (tid < NEXP) {
        float P = 0.f, C = 0.f;
        #pragma unroll
        for (int qq = 0; qq < 16; ++qq) {
            P += red[qq][tid >> 2][tid & 3];
            C += red[qq][tid >> 2][4 + (tid & 3)];
        }
        float val = (C / (float)N_TOKENS) * (P / (float)N_TOKENS);
        #pragma unroll
        for (int off = 32; off >= 1; off >>= 1) val += __shfl_xor(val, off);
        if (tid == 0) out_loss[0] = (float)NEXP * val;
    }
}

extern "C" void kernel_launch(void* const* d_in, const int* in_sizes, int n_in,
                              void* d_out, int out_size, void* d_ws, size_t ws_size,
                              hipStream_t stream) {
    const float* x  = (const float*)d_in[0];
    const float* gw = (const float*)d_in[1];
    float* out   = (float*)d_out;
    float* out_w = out;                        // [N,2] weights
    float* out_i = out + (size_t)N_TOKENS * 2; // [N,2] indices (as floats)
    float* loss  = out + (size_t)N_TOKENS * 4; // scalar
    float*    wsP = (float*)d_ws;                                    // 128 KB
    int*      wsC = (int*)((char*)d_ws + 131072);                    // 128 KB
    _Float16* wh  = (_Float16*)((char*)d_ws + 262144);               // 256 KB
    _Float16* wl  = wh + (size_t)HIDDEN * NEXP;                      // 256 KB
    hipLaunchKernelGGL(wsplit_kernel, dim3(HIDDEN / KSTEP), dim3(256), 0, stream, gw, wh, wl);
    hipLaunchKernelGGL(router_main, dim3(NBLK), dim3(256), 0, stream,
                       x, wh, wl, out_w, out_i, wsP, wsC);
    hipLaunchKernelGGL(router_finalize, dim3(1), dim3(256), 0, stream, wsP, wsC, loss);
}

// Round 11
// 91.513 us; speedup vs baseline: 1.2404x; 1.0042x over previous
//
#include <hip/hip_runtime.h>
#include <math.h>

// MoE router: logits = x @ gate_w  (M=32768, K=2048, N=64 fp32)
// Split-precision MFMA: x,w -> 2 fp16 limbs each; logits = xh*wh + xh*wl + xl*wh.
// Scaling: x*64, w*256 (denormal safety), descale 2^-14 at epilogue.
// R11: main/wsplit identical to R10 (best: 91.9 us). Finalize parallelized into
//      2 stages (64-block partial sums + 1-block combine) to isolate aux cost.
// outputs (concat flat, read back as float32):
//   [0 .. 2N)   top_k_weights [N,2]
//   [2N .. 4N)  top_k_indices [N,2] (as float values)
//   [4N]        load_balance_loss scalar
#define N_TOKENS 32768
#define HIDDEN   2048
#define NEXP     64
#define BM 64                   // tokens per block
#define NWAVE 4                 // 256 threads
#define NBLK (N_TOKENS / BM)    // 512
#define KSTEP 32
#define NSTEP 32                // K-half (1024) / KSTEP
#define XSCALE 64.f
#define WSCALE 256.f
#define DESCALE (1.f / 16384.f)
#define NG 64                   // finalize stage-1 blocks (8 router-blocks each)

typedef __attribute__((ext_vector_type(8))) _Float16 half8;
typedef __attribute__((ext_vector_type(4))) float f32x4;

// ---- kernel 0: split gate_w into 2 fp16 limb planes, MFMA-fragment-packed ----
// plane order: [(S*4 + nt)*64 + lane]*8 + j  <=>  w[32S + (lane>>4)*8 + j][nt*16 + (lane&15)]
__global__ void wsplit_kernel(const float* __restrict__ gw,
                              _Float16* __restrict__ wh, _Float16* __restrict__ wl) {
    __shared__ float tile[KSTEP * NEXP];     // 32 k-rows x 64 experts
    const int S   = blockIdx.x;              // 0..63 K-steps
    const int tid = threadIdx.x;             // 256
    const float4* g4 = reinterpret_cast<const float4*>(gw + (size_t)S * KSTEP * NEXP);
    float4* t4 = reinterpret_cast<float4*>(tile);
    t4[tid]       = g4[tid];
    t4[tid + 256] = g4[tid + 256];
    __syncthreads();
    const int nt  = tid >> 6;
    const int l   = tid & 63;
    const int col = nt * 16 + (l & 15);
    const int kr  = (l >> 4) * 8;
    half8 vh, vl;
    #pragma unroll
    for (int j = 0; j < 8; ++j) {
        const float w = tile[(kr + j) * NEXP + col] * WSCALE;
        const _Float16 hh = (_Float16)w;
        vh[j] = hh;
        vl[j] = (_Float16)(w - (float)hh);
    }
    const size_t off = ((size_t)(S * 4 + nt) * 64 + l) * 8;
    *reinterpret_cast<half8*>(wh + off) = vh;
    *reinterpret_cast<half8*>(wl + off) = vl;
}

__global__ __launch_bounds__(256, 2)
void router_main(const float* __restrict__ x,
                 const _Float16* __restrict__ whp, const _Float16* __restrict__ wlp,
                 float* __restrict__ out_w, float* __restrict__ out_i,
                 float* __restrict__ wsP, int* __restrict__ wsC)
{
    __shared__ float part[2][BM][65];   // K-half partial logits (33.3 KB)
    __shared__ float pred[NWAVE][NEXP];
    __shared__ int   cntl[NEXP];

    const int tid  = threadIdx.x;
    const int lane = tid & 63;
    const int wv   = tid >> 6;
    const int m0   = blockIdx.x * BM;
    if (tid < NEXP) cntl[tid] = 0;

    const int mrow = lane & 15;        // token row within m-tile
    const int kq   = lane >> 4;        // k quad
    const int wtok = (wv >> 1) * 32;   // wave token base: 0 or 32
    const int kh   = wv & 1;           // K-half
    const int Sb   = kh * NSTEP;       // global K-step base

    const float* xb = x + (size_t)(m0 + wtok + mrow) * HIDDEN + (size_t)kh * 1024 + kq * 8;

    f32x4 a[4][2][2];                  // [set][mt][half-of-8] — A prefetch depth 3
    half8 bh[2][4], bl[2][4];          // [set][nt]            — B prefetch depth 1
    f32x4 acc[2][4];
    const f32x4 zero = {0.f, 0.f, 0.f, 0.f};
    #pragma unroll
    for (int mt = 0; mt < 2; ++mt)
        #pragma unroll
        for (int nt = 0; nt < 4; ++nt) acc[mt][nt] = zero;

    #define LOADA(SET, s_) {                                                          \
        _Pragma("unroll")                                                             \
        for (int mt = 0; mt < 2; ++mt) {                                              \
            const float* g_ = xb + (size_t)mt * (16 * HIDDEN) + (s_) * KSTEP;         \
            a[SET][mt][0] = *reinterpret_cast<const f32x4*>(g_);                      \
            a[SET][mt][1] = *reinterpret_cast<const f32x4*>(g_ + 4);                  \
        } }
    #define LOADB(SET, s_) {                                                          \
        const int S_ = Sb + (s_);                                                     \
        _Pragma("unroll")                                                             \
        for (int nt = 0; nt < 4; ++nt) {                                              \
            const size_t o_ = ((size_t)(S_ * 4 + nt) * 64 + lane) * 8;                \
            bh[SET][nt] = *reinterpret_cast<const half8*>(whp + o_);                  \
            bl[SET][nt] = *reinterpret_cast<const half8*>(wlp + o_);                  \
        } }
    #define COMPUTE(AS, BS) {                                                         \
        half8 ah[2], al[2];                                                           \
        _Pragma("unroll")                                                             \
        for (int mt = 0; mt < 2; ++mt)                                                \
            _Pragma("unroll")                                                         \
            for (int h = 0; h < 2; ++h)                                               \
                _Pragma("unroll")                                                     \
                for (int j = 0; j < 4; ++j) {                                         \
                    const float v_ = a[AS][mt][h][j] * XSCALE;                        \
                    const _Float16 hh_ = (_Float16)v_;                                \
                    ah[mt][h * 4 + j] = hh_;                                          \
                    al[mt][h * 4 + j] = (_Float16)(v_ - (float)hh_);                  \
                }                                                                     \
        _Pragma("unroll")                                                             \
        for (int mt = 0; mt < 2; ++mt)                                                \
            _Pragma("unroll")                                                         \
            for (int nt = 0; nt < 4; ++nt) {                                          \
                f32x4 c_ = acc[mt][nt];                                               \
                c_ = __builtin_amdgcn_mfma_f32_16x16x32_f16(ah[mt], bh[BS][nt], c_, 0, 0, 0); \
                c_ = __builtin_amdgcn_mfma_f32_16x16x32_f16(ah[mt], bl[BS][nt], c_, 0, 0, 0); \
                c_ = __builtin_amdgcn_mfma_f32_16x16x32_f16(al[mt], bh[BS][nt], c_, 0, 0, 0); \
                acc[mt][nt] = c_;                                                     \
            } }

    // prologue: A 3 deep, B 1 deep
    LOADA(0, 0); LOADA(1, 1); LOADA(2, 2); LOADB(0, 0);

    // steady state: 4-step body, all set indices static
    for (int t = 0; t < 7; ++t) {
        const int s = t * 4;
        LOADA(3, s + 3); LOADB(1, s + 1); COMPUTE(0, 0);
        LOADA(0, s + 4); LOADB(0, s + 2); COMPUTE(1, 1);
        LOADA(1, s + 5); LOADB(1, s + 3); COMPUTE(2, 0);
        LOADA(2, s + 6); LOADB(0, s + 4); COMPUTE(3, 1);
    }
    // tail: steps 28..31
    LOADA(3, 31); LOADB(1, 29); COMPUTE(0, 0);
    LOADB(0, 30); COMPUTE(1, 1);
    LOADB(1, 31); COMPUTE(2, 0);
    COMPUTE(3, 1);
    #undef LOADA
    #undef LOADB
    #undef COMPUTE

    // dump K-half partials: C/D layout col=lane&15 (expert), row=(lane>>4)*4+r (token)
    #pragma unroll
    for (int mt = 0; mt < 2; ++mt)
        #pragma unroll
        for (int nt = 0; nt < 4; ++nt)
            #pragma unroll
            for (int r = 0; r < 4; ++r)
                part[kh][wtok + mt * 16 + (lane >> 4) * 4 + r][nt * 16 + (lane & 15)] =
                    acc[mt][nt][r] * DESCALE;
    __syncthreads();

    // epilogue: wave wv handles tokens wv*16..+15; lane = expert
    float sumP = 0.f;
    for (int t = 0; t < 16; ++t) {
        const int m = wv * 16 + t;
        const float l = part[0][m][lane] + part[1][m][lane];

        // top-1 (max value, lowest index on tie — matches jax.lax.top_k)
        float v = l; int idx = lane;
        #pragma unroll
        for (int off = 32; off >= 1; off >>= 1) {
            float ov = __shfl_xor(v, off);
            int   oi = __shfl_xor(idx, off);
            if (ov > v || (ov == v && oi < idx)) { v = ov; idx = oi; }
        }
        const float v1 = v; const int i1 = idx;
        // top-2
        v = (lane == i1) ? -INFINITY : l;
        idx = lane;
        #pragma unroll
        for (int off = 32; off >= 1; off >>= 1) {
            float ov = __shfl_xor(v, off);
            int   oi = __shfl_xor(idx, off);
            if (ov > v || (ov == v && oi < idx)) { v = ov; idx = oi; }
        }
        const float v2 = v; const int i2 = idx;
        // softmax over the two top logits (stable: v2 - v1 <= 0)
        const float ed  = expf(v2 - v1);
        const float wt1 = 1.f / (1.f + ed);
        const float wt2 = ed / (1.f + ed);
        // full softmax over 64 experts (max is v1)
        const float p = expf(l - v1);
        float Z = p;
        #pragma unroll
        for (int off = 32; off >= 1; off >>= 1) Z += __shfl_xor(Z, off);
        sumP += p / Z;
        if (lane == 0) {
            const size_t o = (size_t)(m0 + m) * 2;
            out_w[o]     = wt1;
            out_w[o + 1] = wt2;
            out_i[o]     = (float)i1;
            out_i[o + 1] = (float)i2;
            atomicAdd(&cntl[i1], 1);
            atomicAdd(&cntl[i2], 1);
        }
    }
    pred[wv][lane] = sumP;
    __syncthreads();
    if (tid < NEXP) {
        float s = 0.f;
        #pragma unroll
        for (int w2 = 0; w2 < NWAVE; ++w2) s += pred[w2][tid];
        wsP[(size_t)blockIdx.x * NEXP + tid] = s;
        wsC[(size_t)blockIdx.x * NEXP + tid] = cntl[tid];
    }
}

// ---- finalize stage 1: 64 blocks x 1 wave; block g sums router-blocks g*8..g*8+7 ----
__global__ void router_fin1(const float* __restrict__ wsP, const int* __restrict__ wsC,
                            float* __restrict__ Ps1, float* __restrict__ Cs1)
{
    const int g = blockIdx.x;          // 0..63
    const int e = threadIdx.x;         // 64 threads, lane = expert
    float P = 0.f, C = 0.f;
    #pragma unroll
    for (int r = 0; r < 8; ++r) {
        const size_t row = (size_t)(g * 8 + r) * NEXP + e;
        P += wsP[row];
        C += (float)wsC[row];
    }
    Ps1[(size_t)g * NEXP + e] = P;
    Cs1[(size_t)g * NEXP + e] = C;
}

// ---- finalize stage 2: 1 block x 1 wave; combine 64 partials, compute loss ----
__global__ void router_fin2(const float* __restrict__ Ps1, const float* __restrict__ Cs1,
                            float* __restrict__ out_loss)
{
    const int e = threadIdx.x;         // 64 threads
    float P = 0.f, C = 0.f;
    #pragma unroll
    for (int g = 0; g < NG; ++g) {
        P += Ps1[(size_t)g * NEXP + e];
        C += Cs1[(size_t)g * NEXP + e];
    }
    float val = (C / (float)N_TOKENS) * (P / (float)N_TOKENS);
    #pragma unroll
    for (int off = 32; off >= 1; off >>= 1) val += __shfl_xor(val, off);
    if (e == 0) out_loss[0] = (float)NEXP * val;
}

extern "C" void kernel_launch(void* const* d_in, const int* in_sizes, int n_in,
                              void* d_out, int out_size, void* d_ws, size_t ws_size,
                              hipStream_t stream) {
    const float* x  = (const float*)d_in[0];
    const float* gw = (const float*)d_in[1];
    float* out   = (float*)d_out;
    float* out_w = out;                        // [N,2] weights
    float* out_i = out + (size_t)N_TOKENS * 2; // [N,2] indices (as floats)
    float* loss  = out + (size_t)N_TOKENS * 4; // scalar
    float*    wsP = (float*)d_ws;                                    // 128 KB
    int*      wsC = (int*)((char*)d_ws + 131072);                    // 128 KB
    _Float16* wh  = (_Float16*)((char*)d_ws + 262144);               // 256 KB
    _Float16* wl  = wh + (size_t)HIDDEN * NEXP;                      // 256 KB
    float*    Ps1 = (float*)((char*)d_ws + 786432);                  // 16 KB
    float*    Cs1 = Ps1 + NG * NEXP;                                 // 16 KB
    hipLaunchKernelGGL(wsplit_kernel, dim3(HIDDEN / KSTEP), dim3(256), 0, stream, gw, wh, wl);
    hipLaunchKernelGGL(router_main, dim3(NBLK), dim3(256), 0, stream,
                       x, wh, wl, out_w, out_i, wsP, wsC);
    hipLaunchKernelGGL(router_fin1, dim3(NG), dim3(64), 0, stream, wsP, wsC, Ps1, Cs1);
    hipLaunchKernelGGL(router_fin2, dim3(1), dim3(64), 0, stream, Ps1, Cs1, loss);
}